// Round 1
// baseline (123.402 us; speedup 1.0000x reference)
//
#include <hip/hip_runtime.h>
#include <math.h>

#define N 4096
#define B 2048
#define RANK 4
#define ALPHA 0.8862269254527580f   // sqrt(pi)/2
#define INV_N (1.0f / 4096.0f)

#define SPLITS 64
#define RPB (N / SPLITS)            // 64 rows per block in kernel 1
#define R3 16                       // rows per block in kernel 3

// ---------------------------------------------------------------------------
// Kernel 1: partial rank-4 (+z) reduction over row-splits.
// grid (B/256, SPLITS), block 256. Block = 256 cols x RPB rows.
// Each thread owns one column b, loops RPB rows, accumulates
//   a_r += v[n][r] * erf(alpha*h[n][b]),  az += z[n] * erf(alpha*h[n][b])
// v/z rows staged in LDS (wave-uniform reads -> broadcast, conflict-free).
// Writes partials[split][r][b] coalesced (no atomics, no zero-init needed).
// ---------------------------------------------------------------------------
__global__ __launch_bounds__(256) void k_reduce_partial(
    const float* __restrict__ h, const float* __restrict__ v,
    const float* __restrict__ z, float* __restrict__ partials) {
  __shared__ float lv[RPB][RANK];
  __shared__ float lz[RPB];
  const int tid = threadIdx.x;
  const int b = blockIdx.x * 256 + tid;
  const int row0 = blockIdx.y * RPB;

  // cooperative stage of v,z rows for this split
  for (int i = tid; i < RPB * RANK; i += 256) {
    int r = i & (RANK - 1);
    int n = i >> 2;
    lv[n][r] = v[(size_t)(row0 + n) * RANK + r];
  }
  if (tid < RPB) lz[tid] = z[row0 + tid];
  __syncthreads();

  float a0 = 0.f, a1 = 0.f, a2 = 0.f, a3 = 0.f, az = 0.f;
  const float* hp = h + (size_t)row0 * B + b;
#pragma unroll 4
  for (int i = 0; i < RPB; ++i) {
    float phi = erff(ALPHA * hp[(size_t)i * B]);
    a0 = fmaf(lv[i][0], phi, a0);
    a1 = fmaf(lv[i][1], phi, a1);
    a2 = fmaf(lv[i][2], phi, a2);
    a3 = fmaf(lv[i][3], phi, a3);
    az = fmaf(lz[i], phi, az);
  }

  float* pp = partials + ((size_t)blockIdx.y * 5) * B + b;
  pp[0 * B] = a0;
  pp[1 * B] = a1;
  pp[2 * B] = a2;
  pp[3 * B] = a3;
  pp[4 * B] = az;
}

// ---------------------------------------------------------------------------
// Kernel 2: sum the SPLITS partials -> final s[4][B] (ws) and y[B] (d_out).
// 5*B outputs, one thread each; coalesced along b within each split row.
// ---------------------------------------------------------------------------
__global__ __launch_bounds__(256) void k_reduce_final(
    const float* __restrict__ partials, float* __restrict__ sfin,
    float* __restrict__ y) {
  const int o = blockIdx.x * 256 + threadIdx.x;  // [0, 5*B)
  const int r = o / B;
  const int b = o - r * B;
  float s = 0.f;
#pragma unroll 8
  for (int sp = 0; sp < SPLITS; ++sp)
    s += partials[((size_t)sp * 5 + r) * B + b];
  if (r < RANK)
    sfin[(size_t)r * B + b] = s;
  else
    y[b] = s * INV_N;  // y = (z.T @ phi) / N ; 1/4096 is exact
}

// ---------------------------------------------------------------------------
// Kernel 3: h_new[n][b] = (sum_r u[n][r]*s[r][b]) / N + m[n]*x[b]
// grid (B/1024, N/R3), block 256; thread owns 4 consecutive cols (float4).
// s/x hoisted out of the row loop; u/m are block-uniform scalar loads.
// Pure coalesced float4 write stream of 33.5 MB.
// ---------------------------------------------------------------------------
__global__ __launch_bounds__(256) void k_update(
    const float* __restrict__ sfin, const float* __restrict__ u,
    const float* __restrict__ m, const float* __restrict__ x,
    float* __restrict__ hnew) {
  const int b4 = (blockIdx.x * 256 + threadIdx.x) * 4;
  const int row0 = blockIdx.y * R3;

  const float4 s0 = *(const float4*)(sfin + 0 * B + b4);
  const float4 s1 = *(const float4*)(sfin + 1 * B + b4);
  const float4 s2 = *(const float4*)(sfin + 2 * B + b4);
  const float4 s3 = *(const float4*)(sfin + 3 * B + b4);
  const float4 xv = *(const float4*)(x + b4);

#pragma unroll
  for (int i = 0; i < R3; ++i) {
    const int n = row0 + i;
    const float4 uv = *(const float4*)(u + (size_t)n * RANK);
    const float mv = m[n];
    float4 o;
    o.x = fmaf(mv, xv.x,
               (s0.x * uv.x + s1.x * uv.y + s2.x * uv.z + s3.x * uv.w) * INV_N);
    o.y = fmaf(mv, xv.y,
               (s0.y * uv.x + s1.y * uv.y + s2.y * uv.z + s3.y * uv.w) * INV_N);
    o.z = fmaf(mv, xv.z,
               (s0.z * uv.x + s1.z * uv.y + s2.z * uv.z + s3.z * uv.w) * INV_N);
    o.w = fmaf(mv, xv.w,
               (s0.w * uv.x + s1.w * uv.y + s2.w * uv.z + s3.w * uv.w) * INV_N);
    *(float4*)(hnew + (size_t)n * B + b4) = o;
  }
}

// ---------------------------------------------------------------------------
extern "C" void kernel_launch(void* const* d_in, const int* in_sizes, int n_in,
                              void* d_out, int out_size, void* d_ws,
                              size_t ws_size, hipStream_t stream) {
  const float* x = (const float*)d_in[0];  // [1, B]
  const float* h = (const float*)d_in[1];  // [N, B]
  const float* m = (const float*)d_in[2];  // [N, 1]
  const float* u = (const float*)d_in[3];  // [N, RANK]
  const float* v = (const float*)d_in[4];  // [N, RANK]
  const float* z = (const float*)d_in[5];  // [N, 1]

  float* y = (float*)d_out;            // first output: y [1, B]
  float* hnew = (float*)d_out + B;     // second output: h_new [N, B]

  float* partials = (float*)d_ws;                        // [SPLITS][5][B]
  float* sfin = (float*)d_ws + (size_t)SPLITS * 5 * B;   // [RANK][B]
  // ws usage: (64*5*2048 + 4*2048) * 4 B = ~2.6 MB

  k_reduce_partial<<<dim3(B / 256, SPLITS), 256, 0, stream>>>(h, v, z,
                                                              partials);
  k_reduce_final<<<(5 * B) / 256, 256, 0, stream>>>(partials, sfin, y);
  k_update<<<dim3(B / 1024, N / R3), 256, 0, stream>>>(sfin, u, m, x, hnew);
}